// Round 11
// baseline (301.660 us; speedup 1.0000x reference)
//
#include <hip/hip_runtime.h>
#include <stdint.h>

#define DMODEL 1024
#define NHEADS 16
#define DK     64
#define BATCH  4
#define SEQ    2048
#define MROWS  (BATCH*SEQ)   // 8192

typedef __bf16 bf16x8 __attribute__((ext_vector_type(8)));
typedef float  f32x4  __attribute__((ext_vector_type(4)));
typedef float  f32x16 __attribute__((ext_vector_type(16)));

#if defined(__has_builtin)
#if __has_builtin(__builtin_amdgcn_exp2f)
#define EXP2F(x) __builtin_amdgcn_exp2f(x)
#endif
#if __has_builtin(__builtin_amdgcn_permlane32_swap)
#define HAVE_PLSWAP 1
#endif
#endif
#ifndef EXP2F
#define EXP2F(x) exp2f(x)
#endif

__device__ __forceinline__ unsigned short f2bf(float f) {
    unsigned int u = __builtin_bit_cast(unsigned int, f);
    u += 0x7fffu + ((u >> 16) & 1u);   // round-to-nearest-even
    return (unsigned short)(u >> 16);
}

// two f32 -> packed 2x bf16 (v_cvt_pk_bf16_f32, RNE) — r5-verified
__device__ __forceinline__ unsigned int cvtpk(float lo, float hi) {
    unsigned int r;
    asm("v_cvt_pk_bf16_f32 %0, %1, %2" : "=v"(r) : "v"(lo), "v"(hi));
    return r;
}

// v_permlane32_swap_b32: a.hi31..32 <-> b.lo0..31 (register-only, no LDS traffic).
// After: a = {a.lo, b.lo-from-swapped-half}, b = {a.hi, b.hi} per T12 semantics.
__device__ __forceinline__ void permswap(unsigned int& a, unsigned int& b) {
#ifdef HAVE_PLSWAP
    auto r = __builtin_amdgcn_permlane32_swap(a, b, false, false);
    a = (unsigned int)r[0];
    b = (unsigned int)r[1];
#else
    asm("v_permlane32_swap_b32 %0, %1" : "+v"(a), "+v"(b));
#endif
}

// async global->LDS, 16 B per lane, LDS dest = uniform base + lane*16
#define GLDS(gp, lp) __builtin_amdgcn_global_load_lds( \
    (const __attribute__((address_space(1))) unsigned int*)(gp), \
    (__attribute__((address_space(3))) unsigned int*)(lp), 16, 0, 0)

// ------ fused prep: x + 4 weights fp32->bf16, and mask int32 -> float bias -----------
#define XBLK (MROWS * DMODEL / 4 / 256)            // 8192
#define WBLK (4 * DMODEL * DMODEL / 4 / 256)       // 4096
#define MBLK (BATCH * SEQ / 4 / 256)               // 8
__global__ void prep_kernel(const float* __restrict__ x,
                            const float* __restrict__ w0, const float* __restrict__ w1,
                            const float* __restrict__ w2, const float* __restrict__ w3,
                            const int* __restrict__ mask,
                            unsigned short* __restrict__ xb,
                            unsigned short* __restrict__ d0, unsigned short* __restrict__ d1,
                            unsigned short* __restrict__ d2, unsigned short* __restrict__ d3,
                            float* __restrict__ mbf) {
    const int bx = blockIdx.x;
    if (bx >= XBLK + WBLK) {                              // 8 blocks: mask -> bias
        const int i = (bx - XBLK - WBLK) * 256 + threadIdx.x;
        const int4 mi = reinterpret_cast<const int4*>(mask)[i];
        float4 o;
        o.x = mi.x ? 0.f : -1e30f;
        o.y = mi.y ? 0.f : -1e30f;
        o.z = mi.z ? 0.f : -1e30f;
        o.w = mi.w ? 0.f : -1e30f;
        reinterpret_cast<float4*>(mbf)[i] = o;
        return;
    }
    const float* s; unsigned short* d; int i;
    if (bx < XBLK) {                                      // 8192 blocks: x
        s = x; d = xb; i = bx * 256 + threadIdx.x;
    } else {                                              // 4 x 1024 blocks: weights
        const int wb = bx - XBLK;
        const int wsel = wb >> 10;
        i = (wb & 1023) * 256 + threadIdx.x;
        switch (wsel) {
            case 0:  s = w0; d = d0; break;
            case 1:  s = w1; d = d1; break;
            case 2:  s = w2; d = d2; break;
            default: s = w3; d = d3; break;
        }
    }
    const float4 v = reinterpret_cast<const float4*>(s)[i];
    ushort4 o;
    o.x = f2bf(v.x); o.y = f2bf(v.y); o.z = f2bf(v.z); o.w = f2bf(v.w);
    reinterpret_cast<ushort4*>(d)[i] = o;
}

// ---------------- 128x128-tile GEMM, BK=64, LDS staged (r3 known-good) ----------------
// launch_bounds(256,3): 3 blocks/CU. DO NOT raise to 4 — r8 measured: the allocator
// squeezes to 64 VGPR and spills acc to scratch (FETCH 137MB/WRITE 248MB, 2.2x slower).
template<int MODE>
__global__ __launch_bounds__(256, 3) void gemm128(
        const unsigned short* __restrict__ A,
        const unsigned short* __restrict__ W0,
        const unsigned short* __restrict__ W1,
        const unsigned short* __restrict__ W2,
        const float* __restrict__ b0,
        const float* __restrict__ b1,
        const float* __restrict__ b2,
        void* __restrict__ o0, void* __restrict__ o1, void* __restrict__ o2) {
    __shared__ unsigned short As[128 * 64];   // 16 KB, rows of 64 bf16, chunk-swizzled
    __shared__ unsigned short Bs[128 * 64];   // 16 KB
    const int lane = threadIdx.x & 63;
    const int wave = threadIdx.x >> 6;
    const int quad = lane >> 4;
    const int r15  = lane & 15;
    const int wr = wave >> 1, wc = wave & 1;
    const int m0 = blockIdx.y * 128;

    int which, ncol0;
    const unsigned short* W;
    const float* bias;
    if (MODE == 0) {
        which = blockIdx.x >> 3;
        ncol0 = (blockIdx.x & 7) * 128;
        W    = which == 0 ? W0 : (which == 1 ? W1 : W2);
        bias = which == 0 ? b0 : (which == 1 ? b1 : b2);
    } else {
        which = 0; ncol0 = blockIdx.x * 128; W = W0; bias = b0;
    }

    const int srow = lane >> 3;
    const int scg  = (lane & 7) ^ srow;
    const unsigned short* Ag[4];
    const unsigned short* Wg[4];
    #pragma unroll
    for (int j = 0; j < 4; ++j) {
        const int row = (wave * 4 + j) * 8 + srow;
        Ag[j] = A + (m0 + row) * DMODEL + scg * 8;
        Wg[j] = W + (ncol0 + row) * DMODEL + scg * 8;
    }

    f32x4 acc[4][4] = {};
    for (int kk = 0; kk < DMODEL; kk += 64) {
        __syncthreads();
        #pragma unroll
        for (int j = 0; j < 4; ++j) {
            GLDS(Ag[j] + kk, &As[(wave * 4 + j) * 512]);
            GLDS(Wg[j] + kk, &Bs[(wave * 4 + j) * 512]);
        }
        __syncthreads();
        #pragma unroll
        for (int u = 0; u < 2; ++u) {
            bf16x8 af[4], bfx[4];
            const int cs = ((u * 4 + quad) ^ (r15 & 7)) * 8;
            #pragma unroll
            for (int t = 0; t < 4; ++t) {
                af[t]  = *(const bf16x8*)&As[(wr * 64 + t * 16 + r15) * 64 + cs];
                bfx[t] = *(const bf16x8*)&Bs[(wc * 64 + t * 16 + r15) * 64 + cs];
            }
            #pragma unroll
            for (int mt = 0; mt < 4; ++mt)
                #pragma unroll
                for (int nt = 0; nt < 4; ++nt)
                    acc[mt][nt] = __builtin_amdgcn_mfma_f32_16x16x32_bf16(
                        af[mt], bfx[nt], acc[mt][nt], 0, 0, 0);
        }
    }

    #pragma unroll
    for (int mt = 0; mt < 4; ++mt) {
        #pragma unroll
        for (int nt = 0; nt < 4; ++nt) {
            #pragma unroll
            for (int r = 0; r < 4; ++r) {
                const int row = m0 + wr * 64 + mt * 16 + quad * 4 + r;  // C row = quad*4+reg
                const int col = ncol0 + wc * 64 + nt * 16 + r15;        // C col = lane&15
                float v = acc[mt][nt][r] + bias[col];
                if (MODE == 1) {
                    ((float*)o0)[(size_t)row * DMODEL + col] = v;
                } else {
                    if (which == 0) v *= 0.18033688011112042f;  // 0.125*log2(e)
                    const int b = row >> 11, l = row & (SEQ - 1);
                    const int h = col >> 6,  d = col & (DK - 1);
                    const int bh = b * NHEADS + h;
                    unsigned short* ow = (unsigned short*)(which == 0 ? o0 : (which == 1 ? o1 : o2));
                    size_t idx;
                    if (which < 2) idx = ((size_t)bh * SEQ + l) * DK + d;
                    else           idx = (size_t)bh * (SEQ * DK) + (l >> 6) * (DK * 64) + d * 64 + (l & 63);
                    ow[idx] = f2bf(v);
                }
            }
        }
    }
}

// ---------------- Flash attention: 32x32 MFMA, in-register P via permlane32_swap --------
// r5 structure (passed correctness) with the half-swap done by v_permlane32_swap_b32
// (register-only) instead of __shfl_xor (which compiled to ds_bpermute and doubled
// LDS bank conflicts — the r5 regression). K,V double-buffered; mask row in LDS;
// ONE barrier per tile. LDS = 16 (K dbuf) + 16 (V dbuf) + 8 (mask) = 40 KB -> 4 blocks/CU.
__global__ __launch_bounds__(256, 4) void flash_attn(
        const unsigned short* __restrict__ Q,
        const unsigned short* __restrict__ Km,
        const unsigned short* __restrict__ Vm,
        const float* __restrict__ mbf,
        unsigned short* __restrict__ Oa) {
    __shared__ unsigned short Ks[2][64 * 64];   // 16 KB [key][dk] chunk-swizzled, dbuf
    __shared__ unsigned short Vs[2][64 * 64];   // 16 KB [dv][key] chunk-swizzled, dbuf
    __shared__ float maskl[SEQ];                // 8 KB, linear
    const int lane = threadIdx.x & 63;
    const int wave = threadIdx.x >> 6;
    const int q31  = lane & 31;
    const int h    = lane >> 5;

    // XCD-aware remap: each XCD walks one head's 16 q-tiles before moving on
    const int id   = (blockIdx.y << 4) | blockIdx.x;   // gridDim.x == 16
    const int xcd  = id & 7;
    const int slot = id >> 3;                          // 0..127
    const int bh   = xcd + ((slot >> 4) << 3);         // 0..63
    const int qt   = slot & 15;
    const int b = bh >> 4, hd = bh & (NHEADS - 1);
    const int q0 = qt * 128 + wave * 32;

    const unsigned short* Qb = Q  + (size_t)bh * SEQ * DK;
    const unsigned short* Kb = Km + (size_t)bh * SEQ * DK;
    const unsigned short* Vb = Vm + (size_t)bh * SEQ * DK;
    const float* mb = mbf + b * SEQ;

    const int srow = lane >> 3;
    const int soff = srow * 64 + (((lane & 7) ^ srow) * 8);

    // Q fragments (B operand of 32x32x16): col = q31, k = s*16 + h*8 + j
    bf16x8 bq[4];
    #pragma unroll
    for (int s = 0; s < 4; ++s)
        bq[s] = *(const bf16x8*)(Qb + (q0 + q31) * DK + s * 16 + h * 8);

    // prologue: mask row (2 issues), K[0], V[0]
    #pragma unroll
    for (int j = 0; j < 2; ++j)
        GLDS(mb + j * 1024 + wave * 256 + lane * 4, &maskl[j * 1024 + wave * 256]);
    #pragma unroll
    for (int j = 0; j < 2; ++j) {
        const int wseg = wave * 2 + j;
        GLDS(Kb + wseg * 512 + soff, &Ks[0][wseg * 512]);
        GLDS(Vb + wseg * 512 + soff, &Vs[0][wseg * 512]);
    }
    __syncthreads();   // tile 0 + mask resident

    f32x16 oacc0 = {}, oacc1 = {};
    float l_part = 0.f;

    for (int t = 0; t < SEQ / 64; ++t) {
        const int kb = t * 64;
        const int cur = t & 1;

        // prefetch K[t+1], V[t+1] into the other buffers; land under compute below.
        // Safe: buf[cur^1] was last read in iter t-1, whose end barrier all waves passed.
        if (t + 1 < SEQ / 64) {
            const unsigned short* Kg = Kb + (kb + 64) * 64;
            const unsigned short* Vg = Vb + (kb + 64) * 64;
            #pragma unroll
            for (int j = 0; j < 2; ++j) {
                const int wseg = wave * 2 + j;
                GLDS(Kg + wseg * 512 + soff, &Ks[cur ^ 1][wseg * 512]);
                GLDS(Vg + wseg * 512 + soff, &Vs[cur ^ 1][wseg * 512]);
            }
        }

        bf16x8 pa[4];
        #pragma unroll
        for (int kt = 0; kt < 2; ++kt) {
            const int krow = kt * 32 + q31;
            f32x16 z = {};
            __builtin_amdgcn_s_setprio(1);
            #pragma unroll
            for (int s = 0; s < 4; ++s) {
                const bf16x8 ak = *(const bf16x8*)&Ks[cur][krow * 64 + (((2 * s + h) ^ (krow & 7)) * 8)];
                z = __builtin_amdgcn_mfma_f32_32x32x16_bf16(ak, bq[s], z, 0, 0, 0);
            }
            __builtin_amdgcn_s_setprio(0);

            // softmax (log2 domain): p = exp2(z + maskbias); reg r -> key (r&3)+8*(r>>2)+4h
            float pg[4][4];
            #pragma unroll
            for (int g = 0; g < 4; ++g) {
                const float4 m4 = *(const float4*)&maskl[kb + kt * 32 + g * 8 + h * 4];
                pg[g][0] = EXP2F(z[4 * g + 0] + m4.x);
                pg[g][1] = EXP2F(z[4 * g + 1] + m4.y);
                pg[g][2] = EXP2F(z[4 * g + 2] + m4.z);
                pg[g][3] = EXP2F(z[4 * g + 3] + m4.w);
                l_part += (pg[g][0] + pg[g][1]) + (pg[g][2] + pg[g][3]);
            }

            // pack to bf16 + register half-swap -> PV A-fragments (no LDS, no bpermute)
            #pragma unroll
            for (int hf = 0; hf < 2; ++hf) {
                unsigned int Aw = cvtpk(pg[2 * hf][0],     pg[2 * hf][1]);
                unsigned int Bw = cvtpk(pg[2 * hf][2],     pg[2 * hf][3]);
                unsigned int Cw = cvtpk(pg[2 * hf + 1][0], pg[2 * hf + 1][1]);
                unsigned int Dw = cvtpk(pg[2 * hf + 1][2], pg[2 * hf + 1][3]);
                permswap(Aw, Cw);   // Aw -> elems j0,j1 ; Cw -> j4,j5
                permswap(Bw, Dw);   // Bw -> j2,j3 ; Dw -> j6,j7
                uint4 w;
                w.x = Aw; w.y = Bw; w.z = Cw; w.w = Dw;
                pa[2 * kt + hf] = __builtin_bit_cast(bf16x8, w);
            }
        }

        // PV: O[q][dv] += P[q][key] V[key][dv]; B from Vs[dv][key] (dbuf'd)
        __builtin_amdgcn_s_setprio(1);
        #pragma unroll
        for (int s = 0; s < 4; ++s) {
            const int r0 = q31;
            const int r1 = 32 + q31;
            const bf16x8 vf0 = *(const bf16x8*)&Vs[cur][r0 * 64 + (((2 * s + h) ^ (r0 & 7)) * 8)];
            const bf16x8 vf1 = *(const bf16x8*)&Vs[cur][r1 * 64 + (((2 * s + h) ^ (r1 & 7)) * 8)];
            oacc0 = __builtin_amdgcn_mfma_f32_32x32x16_bf16(pa[s], vf0, oacc0, 0, 0, 0);
            oacc1 = __builtin_amdgcn_mfma_f32_32x32x16_bf16(pa[s], vf1, oacc1, 0, 0, 0);
        }
        __builtin_amdgcn_s_setprio(0);

        // ONE barrier per tile: drains vmcnt (prefetch landed under ~2000cy compute),
        // and collectively protects both buffers for the next iteration
        __syncthreads();
    }

    // epilogue: l for q=q31 (both halves), redistribute to C/D rows, divide, store
    const float l = l_part + __shfl_xor(l_part, 32);
    #pragma unroll
    for (int r = 0; r < 16; ++r) {
        const int qloc = (r & 3) + 8 * (r >> 2) + 4 * h;   // C/D row within 32
        const float lq = __shfl(l, qloc);
        const int row = q0 + qloc;
        const size_t base = ((size_t)b * SEQ + row) * DMODEL + hd * DK;
        Oa[base + q31]      = f2bf(oacc0[r] / lq);
        Oa[base + 32 + q31] = f2bf(oacc1[r] / lq);
    }
}

extern "C" void kernel_launch(void* const* d_in, const int* in_sizes, int n_in,
                              void* d_out, int out_size, void* d_ws, size_t ws_size,
                              hipStream_t stream) {
    (void)in_sizes; (void)n_in; (void)out_size; (void)ws_size;
    const float* x  = (const float*)d_in[0];
    const int* mask = (const int*)d_in[1];
    const float* Wq = (const float*)d_in[2];
    const float* bq = (const float*)d_in[3];
    const float* Wk = (const float*)d_in[4];
    const float* bk = (const float*)d_in[5];
    const float* Wv = (const float*)d_in[6];
    const float* bv = (const float*)d_in[7];
    const float* Wo = (const float*)d_in[8];
    const float* bo = (const float*)d_in[9];
    float* out = (float*)d_out;

    char* ws = (char*)d_ws;
    unsigned short* xb  = (unsigned short*)(ws);                                   // 8192x1024 bf16
    unsigned short* wqb = (unsigned short*)(ws + 16777216);                        // 1024x1024 bf16
    unsigned short* wkb = (unsigned short*)(ws + 16777216 + 1 * 2097152);
    unsigned short* wvb = (unsigned short*)(ws + 16777216 + 2 * 2097152);
    unsigned short* wob = (unsigned short*)(ws + 16777216 + 3 * 2097152);
    unsigned short* qb  = (unsigned short*)(ws + 16777216 + 4 * 2097152);          // [BH,L,64]
    unsigned short* kb  = qb  + (size_t)MROWS * DMODEL;                            // [BH,L,64]
    unsigned short* vtb = kb  + (size_t)MROWS * DMODEL;                            // blocked V
    unsigned short* ab  = vtb + (size_t)MROWS * DMODEL;                            // [B,L,DMODEL]
    float*          mbf = (float*)(ab + (size_t)MROWS * DMODEL);                   // [B,L]

    // 4 launches total: prep (x/W cvt + mask bias), QKV gemm, flash, O-proj gemm
    prep_kernel<<<dim3(XBLK + WBLK + MBLK), 256, 0, stream>>>(
        x, Wq, Wk, Wv, Wo, mask, xb, wqb, wkb, wvb, wob, mbf);

    gemm128<0><<<dim3(24, MROWS / 128), 256, 0, stream>>>(
        xb, wqb, wkb, wvb, bq, bk, bv, qb, kb, vtb);

    flash_attn<<<dim3(16, BATCH * NHEADS), 256, 0, stream>>>(qb, kb, vtb, mbf, ab);

    gemm128<1><<<dim3(8, MROWS / 128), 256, 0, stream>>>(
        ab, wob, nullptr, nullptr, bo, nullptr, nullptr, out, nullptr, nullptr);
}

// Round 12
// 299.163 us; speedup vs baseline: 1.0083x; 1.0083x over previous
//
#include <hip/hip_runtime.h>
#include <stdint.h>

#define DMODEL 1024
#define NHEADS 16
#define DK     64
#define BATCH  4
#define SEQ    2048
#define MROWS  (BATCH*SEQ)   // 8192

typedef __bf16 bf16x8 __attribute__((ext_vector_type(8)));
typedef float  f32x4  __attribute__((ext_vector_type(4)));
typedef float  f32x16 __attribute__((ext_vector_type(16)));

#if defined(__has_builtin)
#if __has_builtin(__builtin_amdgcn_exp2f)
#define EXP2F(x) __builtin_amdgcn_exp2f(x)
#endif
#if __has_builtin(__builtin_amdgcn_permlane32_swap)
#define HAVE_PLSWAP 1
#endif
#endif
#ifndef EXP2F
#define EXP2F(x) exp2f(x)
#endif

__device__ __forceinline__ unsigned short f2bf(float f) {
    unsigned int u = __builtin_bit_cast(unsigned int, f);
    u += 0x7fffu + ((u >> 16) & 1u);   // round-to-nearest-even
    return (unsigned short)(u >> 16);
}

// two f32 -> packed 2x bf16 (v_cvt_pk_bf16_f32, RNE) — r5-verified
__device__ __forceinline__ unsigned int cvtpk(float lo, float hi) {
    unsigned int r;
    asm("v_cvt_pk_bf16_f32 %0, %1, %2" : "=v"(r) : "v"(lo), "v"(hi));
    return r;
}

// v_permlane32_swap_b32: half-swap between lane<32 and lane>=32 (register-only).
__device__ __forceinline__ void permswap(unsigned int& a, unsigned int& b) {
#ifdef HAVE_PLSWAP
    auto r = __builtin_amdgcn_permlane32_swap(a, b, false, false);
    a = (unsigned int)r[0];
    b = (unsigned int)r[1];
#else
    asm("v_permlane32_swap_b32 %0, %1" : "+v"(a), "+v"(b));
#endif
}

// async global->LDS, 16 B per lane, LDS dest = uniform base + lane*16
#define GLDS(gp, lp) __builtin_amdgcn_global_load_lds( \
    (const __attribute__((address_space(1))) unsigned int*)(gp), \
    (__attribute__((address_space(3))) unsigned int*)(lp), 16, 0, 0)

// ------ fused prep: x + 4 weights fp32->bf16, and mask int32 -> float bias -----------
#define XBLK (MROWS * DMODEL / 4 / 256)            // 8192
#define WBLK (4 * DMODEL * DMODEL / 4 / 256)       // 4096
#define MBLK (BATCH * SEQ / 4 / 256)               // 8
__global__ void prep_kernel(const float* __restrict__ x,
                            const float* __restrict__ w0, const float* __restrict__ w1,
                            const float* __restrict__ w2, const float* __restrict__ w3,
                            const int* __restrict__ mask,
                            unsigned short* __restrict__ xb,
                            unsigned short* __restrict__ d0, unsigned short* __restrict__ d1,
                            unsigned short* __restrict__ d2, unsigned short* __restrict__ d3,
                            float* __restrict__ mbf) {
    const int bx = blockIdx.x;
    if (bx >= XBLK + WBLK) {                              // 8 blocks: mask -> bias
        const int i = (bx - XBLK - WBLK) * 256 + threadIdx.x;
        const int4 mi = reinterpret_cast<const int4*>(mask)[i];
        float4 o;
        o.x = mi.x ? 0.f : -1e30f;
        o.y = mi.y ? 0.f : -1e30f;
        o.z = mi.z ? 0.f : -1e30f;
        o.w = mi.w ? 0.f : -1e30f;
        reinterpret_cast<float4*>(mbf)[i] = o;
        return;
    }
    const float* s; unsigned short* d; int i;
    if (bx < XBLK) {                                      // 8192 blocks: x
        s = x; d = xb; i = bx * 256 + threadIdx.x;
    } else {                                              // 4 x 1024 blocks: weights
        const int wb = bx - XBLK;
        const int wsel = wb >> 10;
        i = (wb & 1023) * 256 + threadIdx.x;
        switch (wsel) {
            case 0:  s = w0; d = d0; break;
            case 1:  s = w1; d = d1; break;
            case 2:  s = w2; d = d2; break;
            default: s = w3; d = d3; break;
        }
    }
    const float4 v = reinterpret_cast<const float4*>(s)[i];
    ushort4 o;
    o.x = f2bf(v.x); o.y = f2bf(v.y); o.z = f2bf(v.z); o.w = f2bf(v.w);
    reinterpret_cast<ushort4*>(d)[i] = o;
}

// ---------------- 128x128-tile GEMM, BK=64, LDS staged (r3 known-good) ----------------
// launch_bounds(256,3): 3 blocks/CU. DO NOT raise to 4 — r8 measured: the allocator
// squeezes to 64 VGPR and spills acc to scratch (FETCH 137MB/WRITE 248MB, 2.2x slower).
template<int MODE>
__global__ __launch_bounds__(256, 3) void gemm128(
        const unsigned short* __restrict__ A,
        const unsigned short* __restrict__ W0,
        const unsigned short* __restrict__ W1,
        const unsigned short* __restrict__ W2,
        const float* __restrict__ b0,
        const float* __restrict__ b1,
        const float* __restrict__ b2,
        void* __restrict__ o0, void* __restrict__ o1, void* __restrict__ o2) {
    __shared__ unsigned short As[128 * 64];   // 16 KB, rows of 64 bf16, chunk-swizzled
    __shared__ unsigned short Bs[128 * 64];   // 16 KB
    const int lane = threadIdx.x & 63;
    const int wave = threadIdx.x >> 6;
    const int quad = lane >> 4;
    const int r15  = lane & 15;
    const int wr = wave >> 1, wc = wave & 1;
    const int m0 = blockIdx.y * 128;

    int which, ncol0;
    const unsigned short* W;
    const float* bias;
    if (MODE == 0) {
        which = blockIdx.x >> 3;
        ncol0 = (blockIdx.x & 7) * 128;
        W    = which == 0 ? W0 : (which == 1 ? W1 : W2);
        bias = which == 0 ? b0 : (which == 1 ? b1 : b2);
    } else {
        which = 0; ncol0 = blockIdx.x * 128; W = W0; bias = b0;
    }

    const int srow = lane >> 3;
    const int scg  = (lane & 7) ^ srow;
    const unsigned short* Ag[4];
    const unsigned short* Wg[4];
    #pragma unroll
    for (int j = 0; j < 4; ++j) {
        const int row = (wave * 4 + j) * 8 + srow;
        Ag[j] = A + (m0 + row) * DMODEL + scg * 8;
        Wg[j] = W + (ncol0 + row) * DMODEL + scg * 8;
    }

    f32x4 acc[4][4] = {};
    for (int kk = 0; kk < DMODEL; kk += 64) {
        __syncthreads();
        #pragma unroll
        for (int j = 0; j < 4; ++j) {
            GLDS(Ag[j] + kk, &As[(wave * 4 + j) * 512]);
            GLDS(Wg[j] + kk, &Bs[(wave * 4 + j) * 512]);
        }
        __syncthreads();
        #pragma unroll
        for (int u = 0; u < 2; ++u) {
            bf16x8 af[4], bfx[4];
            const int cs = ((u * 4 + quad) ^ (r15 & 7)) * 8;
            #pragma unroll
            for (int t = 0; t < 4; ++t) {
                af[t]  = *(const bf16x8*)&As[(wr * 64 + t * 16 + r15) * 64 + cs];
                bfx[t] = *(const bf16x8*)&Bs[(wc * 64 + t * 16 + r15) * 64 + cs];
            }
            #pragma unroll
            for (int mt = 0; mt < 4; ++mt)
                #pragma unroll
                for (int nt = 0; nt < 4; ++nt)
                    acc[mt][nt] = __builtin_amdgcn_mfma_f32_16x16x32_bf16(
                        af[mt], bfx[nt], acc[mt][nt], 0, 0, 0);
        }
    }

    #pragma unroll
    for (int mt = 0; mt < 4; ++mt) {
        #pragma unroll
        for (int nt = 0; nt < 4; ++nt) {
            #pragma unroll
            for (int r = 0; r < 4; ++r) {
                const int row = m0 + wr * 64 + mt * 16 + quad * 4 + r;  // C row = quad*4+reg
                const int col = ncol0 + wc * 64 + nt * 16 + r15;        // C col = lane&15
                float v = acc[mt][nt][r] + bias[col];
                if (MODE == 1) {
                    ((float*)o0)[(size_t)row * DMODEL + col] = v;
                } else {
                    if (which == 0) v *= 0.18033688011112042f;  // 0.125*log2(e)
                    const int b = row >> 11, l = row & (SEQ - 1);
                    const int h = col >> 6,  d = col & (DK - 1);
                    const int bh = b * NHEADS + h;
                    unsigned short* ow = (unsigned short*)(which == 0 ? o0 : (which == 1 ? o1 : o2));
                    size_t idx;
                    if (which < 2) idx = ((size_t)bh * SEQ + l) * DK + d;
                    else           idx = (size_t)bh * (SEQ * DK) + (l >> 6) * (DK * 64) + d * 64 + (l & 63);
                    ow[idx] = f2bf(v);
                }
            }
        }
    }
}

// ---------------- Flash attention: 32x32 MFMA, in-register P via permlane32_swap --------
// r11 structure (94.3 us measured): register half-swap, K/V double-buffered, mask in LDS,
// ONE barrier per tile. LDS = 16 + 16 + 8 = 40 KB -> 4 blocks/CU.
// Change vs r11: l_part accumulated as float2 (pairwise packed adds).
__global__ __launch_bounds__(256, 4) void flash_attn(
        const unsigned short* __restrict__ Q,
        const unsigned short* __restrict__ Km,
        const unsigned short* __restrict__ Vm,
        const float* __restrict__ mbf,
        unsigned short* __restrict__ Oa) {
    __shared__ unsigned short Ks[2][64 * 64];   // 16 KB [key][dk] chunk-swizzled, dbuf
    __shared__ unsigned short Vs[2][64 * 64];   // 16 KB [dv][key] chunk-swizzled, dbuf
    __shared__ float maskl[SEQ];                // 8 KB, linear
    const int lane = threadIdx.x & 63;
    const int wave = threadIdx.x >> 6;
    const int q31  = lane & 31;
    const int h    = lane >> 5;

    // XCD-aware remap: each XCD walks one head's 16 q-tiles before moving on
    const int id   = (blockIdx.y << 4) | blockIdx.x;   // gridDim.x == 16
    const int xcd  = id & 7;
    const int slot = id >> 3;                          // 0..127
    const int bh   = xcd + ((slot >> 4) << 3);         // 0..63
    const int qt   = slot & 15;
    const int b = bh >> 4, hd = bh & (NHEADS - 1);
    const int q0 = qt * 128 + wave * 32;

    const unsigned short* Qb = Q  + (size_t)bh * SEQ * DK;
    const unsigned short* Kb = Km + (size_t)bh * SEQ * DK;
    const unsigned short* Vb = Vm + (size_t)bh * SEQ * DK;
    const float* mb = mbf + b * SEQ;

    const int srow = lane >> 3;
    const int soff = srow * 64 + (((lane & 7) ^ srow) * 8);

    // Q fragments (B operand of 32x32x16): col = q31, k = s*16 + h*8 + j
    bf16x8 bq[4];
    #pragma unroll
    for (int s = 0; s < 4; ++s)
        bq[s] = *(const bf16x8*)(Qb + (q0 + q31) * DK + s * 16 + h * 8);

    // prologue: mask row (2 issues), K[0], V[0]
    #pragma unroll
    for (int j = 0; j < 2; ++j)
        GLDS(mb + j * 1024 + wave * 256 + lane * 4, &maskl[j * 1024 + wave * 256]);
    #pragma unroll
    for (int j = 0; j < 2; ++j) {
        const int wseg = wave * 2 + j;
        GLDS(Kb + wseg * 512 + soff, &Ks[0][wseg * 512]);
        GLDS(Vb + wseg * 512 + soff, &Vs[0][wseg * 512]);
    }
    __syncthreads();   // tile 0 + mask resident

    f32x16 oacc0 = {}, oacc1 = {};
    float2 lp = {0.f, 0.f};

    for (int t = 0; t < SEQ / 64; ++t) {
        const int kb = t * 64;
        const int cur = t & 1;

        // prefetch K[t+1], V[t+1] into the other buffers; land under compute below.
        if (t + 1 < SEQ / 64) {
            const unsigned short* Kg = Kb + (kb + 64) * 64;
            const unsigned short* Vg = Vb + (kb + 64) * 64;
            #pragma unroll
            for (int j = 0; j < 2; ++j) {
                const int wseg = wave * 2 + j;
                GLDS(Kg + wseg * 512 + soff, &Ks[cur ^ 1][wseg * 512]);
                GLDS(Vg + wseg * 512 + soff, &Vs[cur ^ 1][wseg * 512]);
            }
        }

        bf16x8 pa[4];
        #pragma unroll
        for (int kt = 0; kt < 2; ++kt) {
            const int krow = kt * 32 + q31;
            f32x16 z = {};
            __builtin_amdgcn_s_setprio(1);
            #pragma unroll
            for (int s = 0; s < 4; ++s) {
                const bf16x8 ak = *(const bf16x8*)&Ks[cur][krow * 64 + (((2 * s + h) ^ (krow & 7)) * 8)];
                z = __builtin_amdgcn_mfma_f32_32x32x16_bf16(ak, bq[s], z, 0, 0, 0);
            }
            __builtin_amdgcn_s_setprio(0);

            // softmax (log2 domain): p = exp2(z + maskbias); reg r -> key (r&3)+8*(r>>2)+4h
            float pg[4][4];
            #pragma unroll
            for (int g = 0; g < 4; ++g) {
                const float4 m4 = *(const float4*)&maskl[kb + kt * 32 + g * 8 + h * 4];
                pg[g][0] = EXP2F(z[4 * g + 0] + m4.x);
                pg[g][1] = EXP2F(z[4 * g + 1] + m4.y);
                pg[g][2] = EXP2F(z[4 * g + 2] + m4.z);
                pg[g][3] = EXP2F(z[4 * g + 3] + m4.w);
                lp.x += pg[g][0] + pg[g][2];
                lp.y += pg[g][1] + pg[g][3];
            }

            // pack to bf16 + register half-swap -> PV A-fragments (no LDS, no bpermute)
            #pragma unroll
            for (int hf = 0; hf < 2; ++hf) {
                unsigned int Aw = cvtpk(pg[2 * hf][0],     pg[2 * hf][1]);
                unsigned int Bw = cvtpk(pg[2 * hf][2],     pg[2 * hf][3]);
                unsigned int Cw = cvtpk(pg[2 * hf + 1][0], pg[2 * hf + 1][1]);
                unsigned int Dw = cvtpk(pg[2 * hf + 1][2], pg[2 * hf + 1][3]);
                permswap(Aw, Cw);   // Aw -> elems j0,j1 ; Cw -> j4,j5
                permswap(Bw, Dw);   // Bw -> j2,j3 ; Dw -> j6,j7
                uint4 w;
                w.x = Aw; w.y = Bw; w.z = Cw; w.w = Dw;
                pa[2 * kt + hf] = __builtin_bit_cast(bf16x8, w);
            }
        }

        // PV: O[q][dv] += P[q][key] V[key][dv]; B from Vs[dv][key] (dbuf'd)
        __builtin_amdgcn_s_setprio(1);
        #pragma unroll
        for (int s = 0; s < 4; ++s) {
            const int r0 = q31;
            const int r1 = 32 + q31;
            const bf16x8 vf0 = *(const bf16x8*)&Vs[cur][r0 * 64 + (((2 * s + h) ^ (r0 & 7)) * 8)];
            const bf16x8 vf1 = *(const bf16x8*)&Vs[cur][r1 * 64 + (((2 * s + h) ^ (r1 & 7)) * 8)];
            oacc0 = __builtin_amdgcn_mfma_f32_32x32x16_bf16(pa[s], vf0, oacc0, 0, 0, 0);
            oacc1 = __builtin_amdgcn_mfma_f32_32x32x16_bf16(pa[s], vf1, oacc1, 0, 0, 0);
        }
        __builtin_amdgcn_s_setprio(0);

        // ONE barrier per tile: drains vmcnt (prefetch landed under ~2000cy compute),
        // and collectively protects both buffers for the next iteration
        __syncthreads();
    }

    // epilogue: l for q=q31 (both halves), redistribute to C/D rows, divide, store
    const float l_own = lp.x + lp.y;
    const float l = l_own + __shfl_xor(l_own, 32);
    #pragma unroll
    for (int r = 0; r < 16; ++r) {
        const int qloc = (r & 3) + 8 * (r >> 2) + 4 * h;   // C/D row within 32
        const float lq = __shfl(l, qloc);
        const int row = q0 + qloc;
        const size_t base = ((size_t)b * SEQ + row) * DMODEL + hd * DK;
        Oa[base + q31]      = f2bf(oacc0[r] / lq);
        Oa[base + 32 + q31] = f2bf(oacc1[r] / lq);
    }
}

extern "C" void kernel_launch(void* const* d_in, const int* in_sizes, int n_in,
                              void* d_out, int out_size, void* d_ws, size_t ws_size,
                              hipStream_t stream) {
    (void)in_sizes; (void)n_in; (void)out_size; (void)ws_size;
    const float* x  = (const float*)d_in[0];
    const int* mask = (const int*)d_in[1];
    const float* Wq = (const float*)d_in[2];
    const float* bq = (const float*)d_in[3];
    const float* Wk = (const float*)d_in[4];
    const float* bk = (const float*)d_in[5];
    const float* Wv = (const float*)d_in[6];
    const float* bv = (const float*)d_in[7];
    const float* Wo = (const float*)d_in[8];
    const float* bo = (const float*)d_in[9];
    float* out = (float*)d_out;

    char* ws = (char*)d_ws;
    unsigned short* xb  = (unsigned short*)(ws);                                   // 8192x1024 bf16
    unsigned short* wqb = (unsigned short*)(ws + 16777216);                        // 1024x1024 bf16
    unsigned short* wkb = (unsigned short*)(ws + 16777216 + 1 * 2097152);
    unsigned short* wvb = (unsigned short*)(ws + 16777216 + 2 * 2097152);
    unsigned short* wob = (unsigned short*)(ws + 16777216 + 3 * 2097152);
    unsigned short* qb  = (unsigned short*)(ws + 16777216 + 4 * 2097152);          // [BH,L,64]
    unsigned short* kb  = qb  + (size_t)MROWS * DMODEL;                            // [BH,L,64]
    unsigned short* vtb = kb  + (size_t)MROWS * DMODEL;                            // blocked V
    unsigned short* ab  = vtb + (size_t)MROWS * DMODEL;                            // [B,L,DMODEL]
    float*          mbf = (float*)(ab + (size_t)MROWS * DMODEL);                   // [B,L]

    // 4 launches total: prep (x/W cvt + mask bias), QKV gemm, flash, O-proj gemm
    prep_kernel<<<dim3(XBLK + WBLK + MBLK), 256, 0, stream>>>(
        x, Wq, Wk, Wv, Wo, mask, xb, wqb, wkb, wvb, wob, mbf);

    gemm128<0><<<dim3(24, MROWS / 128), 256, 0, stream>>>(
        xb, wqb, wkb, wvb, bq, bk, bv, qb, kb, vtb);

    flash_attn<<<dim3(16, BATCH * NHEADS), 256, 0, stream>>>(qb, kb, vtb, mbf, ab);

    gemm128<1><<<dim3(8, MROWS / 128), 256, 0, stream>>>(
        ab, wob, nullptr, nullptr, bo, nullptr, nullptr, out, nullptr, nullptr);
}

// Round 15
// 293.947 us; speedup vs baseline: 1.0262x; 1.0177x over previous
//
#include <hip/hip_runtime.h>
#include <stdint.h>

#define DMODEL 1024
#define NHEADS 16
#define DK     64
#define BATCH  4
#define SEQ    2048
#define MROWS  (BATCH*SEQ)   // 8192

typedef __bf16 bf16x8 __attribute__((ext_vector_type(8)));
typedef float  f32x4  __attribute__((ext_vector_type(4)));
typedef float  f32x16 __attribute__((ext_vector_type(16)));

#if defined(__has_builtin)
#if __has_builtin(__builtin_amdgcn_exp2f)
#define EXP2F(x) __builtin_amdgcn_exp2f(x)
#endif
#if __has_builtin(__builtin_amdgcn_permlane32_swap)
#define HAVE_PLSWAP 1
#endif
#endif
#ifndef EXP2F
#define EXP2F(x) exp2f(x)
#endif

__device__ __forceinline__ unsigned short f2bf(float f) {
    unsigned int u = __builtin_bit_cast(unsigned int, f);
    u += 0x7fffu + ((u >> 16) & 1u);   // round-to-nearest-even
    return (unsigned short)(u >> 16);
}

// two f32 -> packed 2x bf16 (v_cvt_pk_bf16_f32, RNE)
__device__ __forceinline__ unsigned int cvtpk(float lo, float hi) {
    unsigned int r;
    asm("v_cvt_pk_bf16_f32 %0, %1, %2" : "=v"(r) : "v"(lo), "v"(hi));
    return r;
}

// v_permlane32_swap_b32: half-swap between lane<32 and lane>=32 (register-only).
__device__ __forceinline__ void permswap(unsigned int& a, unsigned int& b) {
#ifdef HAVE_PLSWAP
    auto r = __builtin_amdgcn_permlane32_swap(a, b, false, false);
    a = (unsigned int)r[0];
    b = (unsigned int)r[1];
#else
    asm("v_permlane32_swap_b32 %0, %1" : "+v"(a), "+v"(b));
#endif
}

// async global->LDS, 16 B per lane, LDS dest = uniform base + lane*16
#define GLDS(gp, lp) __builtin_amdgcn_global_load_lds( \
    (const __attribute__((address_space(1))) unsigned int*)(gp), \
    (__attribute__((address_space(3))) unsigned int*)(lp), 16, 0, 0)

// ------ fused prep: x + 4 weights fp32->bf16, and mask int32 -> float bias -----------
#define XBLK (MROWS * DMODEL / 4 / 256)            // 8192
#define WBLK (4 * DMODEL * DMODEL / 4 / 256)       // 4096
#define MBLK (BATCH * SEQ / 4 / 256)               // 8
__global__ void prep_kernel(const float* __restrict__ x,
                            const float* __restrict__ w0, const float* __restrict__ w1,
                            const float* __restrict__ w2, const float* __restrict__ w3,
                            const int* __restrict__ mask,
                            unsigned short* __restrict__ xb,
                            unsigned short* __restrict__ d0, unsigned short* __restrict__ d1,
                            unsigned short* __restrict__ d2, unsigned short* __restrict__ d3,
                            float* __restrict__ mbf) {
    const int bx = blockIdx.x;
    if (bx >= XBLK + WBLK) {                              // 8 blocks: mask -> bias
        const int i = (bx - XBLK - WBLK) * 256 + threadIdx.x;
        const int4 mi = reinterpret_cast<const int4*>(mask)[i];
        float4 o;
        o.x = mi.x ? 0.f : -1e30f;
        o.y = mi.y ? 0.f : -1e30f;
        o.z = mi.z ? 0.f : -1e30f;
        o.w = mi.w ? 0.f : -1e30f;
        reinterpret_cast<float4*>(mbf)[i] = o;
        return;
    }
    const float* s; unsigned short* d; int i;
    if (bx < XBLK) {                                      // 8192 blocks: x
        s = x; d = xb; i = bx * 256 + threadIdx.x;
    } else {                                              // 4 x 1024 blocks: weights
        const int wb = bx - XBLK;
        const int wsel = wb >> 10;
        i = (wb & 1023) * 256 + threadIdx.x;
        switch (wsel) {
            case 0:  s = w0; d = d0; break;
            case 1:  s = w1; d = d1; break;
            case 2:  s = w2; d = d2; break;
            default: s = w3; d = d3; break;
        }
    }
    const float4 v = reinterpret_cast<const float4*>(s)[i];
    ushort4 o;
    o.x = f2bf(v.x); o.y = f2bf(v.y); o.z = f2bf(v.z); o.w = f2bf(v.w);
    reinterpret_cast<ushort4*>(d)[i] = o;
}

// ---------------- 128x128-tile GEMM, BK=64, LDS staged (r3 known-good) ----------------
// launch_bounds(256,3): 3 blocks/CU. DO NOT raise to 4 — r8 measured: the allocator
// squeezes to 64 VGPR and spills acc to scratch (FETCH 137MB/WRITE 248MB, 2.2x slower).
template<int MODE>
__global__ __launch_bounds__(256, 3) void gemm128(
        const unsigned short* __restrict__ A,
        const unsigned short* __restrict__ W0,
        const unsigned short* __restrict__ W1,
        const unsigned short* __restrict__ W2,
        const float* __restrict__ b0,
        const float* __restrict__ b1,
        const float* __restrict__ b2,
        void* __restrict__ o0, void* __restrict__ o1, void* __restrict__ o2) {
    __shared__ unsigned short As[128 * 64];   // 16 KB, rows of 64 bf16, chunk-swizzled
    __shared__ unsigned short Bs[128 * 64];   // 16 KB
    const int lane = threadIdx.x & 63;
    const int wave = threadIdx.x >> 6;
    const int quad = lane >> 4;
    const int r15  = lane & 15;
    const int wr = wave >> 1, wc = wave & 1;
    const int m0 = blockIdx.y * 128;

    int which, ncol0;
    const unsigned short* W;
    const float* bias;
    if (MODE == 0) {
        which = blockIdx.x >> 3;
        ncol0 = (blockIdx.x & 7) * 128;
        W    = which == 0 ? W0 : (which == 1 ? W1 : W2);
        bias = which == 0 ? b0 : (which == 1 ? b1 : b2);
    } else {
        which = 0; ncol0 = blockIdx.x * 128; W = W0; bias = b0;
    }

    const int srow = lane >> 3;
    const int scg  = (lane & 7) ^ srow;
    const unsigned short* Ag[4];
    const unsigned short* Wg[4];
    #pragma unroll
    for (int j = 0; j < 4; ++j) {
        const int row = (wave * 4 + j) * 8 + srow;
        Ag[j] = A + (m0 + row) * DMODEL + scg * 8;
        Wg[j] = W + (ncol0 + row) * DMODEL + scg * 8;
    }

    f32x4 acc[4][4] = {};
    for (int kk = 0; kk < DMODEL; kk += 64) {
        __syncthreads();
        #pragma unroll
        for (int j = 0; j < 4; ++j) {
            GLDS(Ag[j] + kk, &As[(wave * 4 + j) * 512]);
            GLDS(Wg[j] + kk, &Bs[(wave * 4 + j) * 512]);
        }
        __syncthreads();
        #pragma unroll
        for (int u = 0; u < 2; ++u) {
            bf16x8 af[4], bfx[4];
            const int cs = ((u * 4 + quad) ^ (r15 & 7)) * 8;
            #pragma unroll
            for (int t = 0; t < 4; ++t) {
                af[t]  = *(const bf16x8*)&As[(wr * 64 + t * 16 + r15) * 64 + cs];
                bfx[t] = *(const bf16x8*)&Bs[(wc * 64 + t * 16 + r15) * 64 + cs];
            }
            #pragma unroll
            for (int mt = 0; mt < 4; ++mt)
                #pragma unroll
                for (int nt = 0; nt < 4; ++nt)
                    acc[mt][nt] = __builtin_amdgcn_mfma_f32_16x16x32_bf16(
                        af[mt], bfx[nt], acc[mt][nt], 0, 0, 0);
        }
    }

    #pragma unroll
    for (int mt = 0; mt < 4; ++mt) {
        #pragma unroll
        for (int nt = 0; nt < 4; ++nt) {
            #pragma unroll
            for (int r = 0; r < 4; ++r) {
                const int row = m0 + wr * 64 + mt * 16 + quad * 4 + r;  // C row = quad*4+reg
                const int col = ncol0 + wc * 64 + nt * 16 + r15;        // C col = lane&15
                float v = acc[mt][nt][r] + bias[col];
                if (MODE == 1) {
                    ((float*)o0)[(size_t)row * DMODEL + col] = v;
                } else {
                    if (which == 0) v *= 0.18033688011112042f;  // 0.125*log2(e)
                    const int b = row >> 11, l = row & (SEQ - 1);
                    const int h = col >> 6,  d = col & (DK - 1);
                    const int bh = b * NHEADS + h;
                    unsigned short* ow = (unsigned short*)(which == 0 ? o0 : (which == 1 ? o1 : o2));
                    size_t idx;
                    if (which < 2) idx = ((size_t)bh * SEQ + l) * DK + d;
                    else           idx = (size_t)bh * (SEQ * DK) + (l >> 6) * (DK * 64) + d * 64 + (l & 63);
                    ow[idx] = f2bf(v);
                }
            }
        }
    }
}

// ---------------- Flash attention: 32x32 MFMA, in-register P via permlane32_swap --------
// Register half-swap (no bpermute), K/V double-buffered, mask in LDS, ONE barrier/tile.
// LDS = 16 + 16 + 8 = 40 KB -> 4 blocks/CU. Measured 93.2 us (r12).
__global__ __launch_bounds__(256, 4) void flash_attn(
        const unsigned short* __restrict__ Q,
        const unsigned short* __restrict__ Km,
        const unsigned short* __restrict__ Vm,
        const float* __restrict__ mbf,
        unsigned short* __restrict__ Oa) {
    __shared__ unsigned short Ks[2][64 * 64];   // 16 KB [key][dk] chunk-swizzled, dbuf
    __shared__ unsigned short Vs[2][64 * 64];   // 16 KB [dv][key] chunk-swizzled, dbuf
    __shared__ float maskl[SEQ];                // 8 KB, linear
    const int lane = threadIdx.x & 63;
    const int wave = threadIdx.x >> 6;
    const int q31  = lane & 31;
    const int h    = lane >> 5;

    // XCD-aware remap: each XCD walks one head's 16 q-tiles before moving on
    const int id   = (blockIdx.y << 4) | blockIdx.x;   // gridDim.x == 16
    const int xcd  = id & 7;
    const int slot = id >> 3;                          // 0..127
    const int bh   = xcd + ((slot >> 4) << 3);         // 0..63
    const int qt   = slot & 15;
    const int b = bh >> 4, hd = bh & (NHEADS - 1);
    const int q0 = qt * 128 + wave * 32;

    const unsigned short* Qb = Q  + (size_t)bh * SEQ * DK;
    const unsigned short* Kb = Km + (size_t)bh * SEQ * DK;
    const unsigned short* Vb = Vm + (size_t)bh * SEQ * DK;
    const float* mb = mbf + b * SEQ;

    const int srow = lane >> 3;
    const int soff = srow * 64 + (((lane & 7) ^ srow) * 8);

    // Q fragments (B operand of 32x32x16): col = q31, k = s*16 + h*8 + j
    bf16x8 bq[4];
    #pragma unroll
    for (int s = 0; s < 4; ++s)
        bq[s] = *(const bf16x8*)(Qb + (q0 + q31) * DK + s * 16 + h * 8);

    // prologue: mask row (2 issues), K[0], V[0]
    #pragma unroll
    for (int j = 0; j < 2; ++j)
        GLDS(mb + j * 1024 + wave * 256 + lane * 4, &maskl[j * 1024 + wave * 256]);
    #pragma unroll
    for (int j = 0; j < 2; ++j) {
        const int wseg = wave * 2 + j;
        GLDS(Kb + wseg * 512 + soff, &Ks[0][wseg * 512]);
        GLDS(Vb + wseg * 512 + soff, &Vs[0][wseg * 512]);
    }
    __syncthreads();   // tile 0 + mask resident

    f32x16 oacc0 = {}, oacc1 = {};
    float2 lp = {0.f, 0.f};

    for (int t = 0; t < SEQ / 64; ++t) {
        const int kb = t * 64;
        const int cur = t & 1;

        // prefetch K[t+1], V[t+1] into the other buffers; land under compute below.
        if (t + 1 < SEQ / 64) {
            const unsigned short* Kg = Kb + (kb + 64) * 64;
            const unsigned short* Vg = Vb + (kb + 64) * 64;
            #pragma unroll
            for (int j = 0; j < 2; ++j) {
                const int wseg = wave * 2 + j;
                GLDS(Kg + wseg * 512 + soff, &Ks[cur ^ 1][wseg * 512]);
                GLDS(Vg + wseg * 512 + soff, &Vs[cur ^ 1][wseg * 512]);
            }
        }

        bf16x8 pa[4];
        #pragma unroll
        for (int kt = 0; kt < 2; ++kt) {
            const int krow = kt * 32 + q31;
            f32x16 z = {};
            __builtin_amdgcn_s_setprio(1);
            #pragma unroll
            for (int s = 0; s < 4; ++s) {
                const bf16x8 ak = *(const bf16x8*)&Ks[cur][krow * 64 + (((2 * s + h) ^ (krow & 7)) * 8)];
                z = __builtin_amdgcn_mfma_f32_32x32x16_bf16(ak, bq[s], z, 0, 0, 0);
            }
            __builtin_amdgcn_s_setprio(0);

            // softmax (log2 domain): p = exp2(z + maskbias); reg r -> key (r&3)+8*(r>>2)+4h
            float pg[4][4];
            #pragma unroll
            for (int g = 0; g < 4; ++g) {
                const float4 m4 = *(const float4*)&maskl[kb + kt * 32 + g * 8 + h * 4];
                pg[g][0] = EXP2F(z[4 * g + 0] + m4.x);
                pg[g][1] = EXP2F(z[4 * g + 1] + m4.y);
                pg[g][2] = EXP2F(z[4 * g + 2] + m4.z);
                pg[g][3] = EXP2F(z[4 * g + 3] + m4.w);
                lp.x += pg[g][0] + pg[g][2];
                lp.y += pg[g][1] + pg[g][3];
            }

            // pack to bf16 + register half-swap -> PV A-fragments (no LDS, no bpermute)
            #pragma unroll
            for (int hf = 0; hf < 2; ++hf) {
                unsigned int Aw = cvtpk(pg[2 * hf][0],     pg[2 * hf][1]);
                unsigned int Bw = cvtpk(pg[2 * hf][2],     pg[2 * hf][3]);
                unsigned int Cw = cvtpk(pg[2 * hf + 1][0], pg[2 * hf + 1][1]);
                unsigned int Dw = cvtpk(pg[2 * hf + 1][2], pg[2 * hf + 1][3]);
                permswap(Aw, Cw);   // Aw -> elems j0,j1 ; Cw -> j4,j5
                permswap(Bw, Dw);   // Bw -> j2,j3 ; Dw -> j6,j7
                uint4 w;
                w.x = Aw; w.y = Bw; w.z = Cw; w.w = Dw;
                pa[2 * kt + hf] = __builtin_bit_cast(bf16x8, w);
            }
        }

        // PV: O[q][dv] += P[q][key] V[key][dv]; B from Vs[dv][key] (dbuf'd)
        __builtin_amdgcn_s_setprio(1);
        #pragma unroll
        for (int s = 0; s < 4; ++s) {
            const int r0 = q31;
            const int r1 = 32 + q31;
            const bf16x8 vf0 = *(const bf16x8*)&Vs[cur][r0 * 64 + (((2 * s + h) ^ (r0 & 7)) * 8)];
            const bf16x8 vf1 = *(const bf16x8*)&Vs[cur][r1 * 64 + (((2 * s + h) ^ (r1 & 7)) * 8)];
            oacc0 = __builtin_amdgcn_mfma_f32_32x32x16_bf16(pa[s], vf0, oacc0, 0, 0, 0);
            oacc1 = __builtin_amdgcn_mfma_f32_32x32x16_bf16(pa[s], vf1, oacc1, 0, 0, 0);
        }
        __builtin_amdgcn_s_setprio(0);

        // ONE barrier per tile: drains vmcnt (prefetch landed under compute),
        // and collectively protects both buffers for the next iteration
        __syncthreads();
    }

    // epilogue: l for q=q31 (both halves), redistribute to C/D rows, divide, store
    const float l_own = lp.x + lp.y;
    const float l = l_own + __shfl_xor(l_own, 32);
    #pragma unroll
    for (int r = 0; r < 16; ++r) {
        const int qloc = (r & 3) + 8 * (r >> 2) + 4 * h;   // C/D row within 32
        const float lq = __shfl(l, qloc);
        const int row = q0 + qloc;
        const size_t base = ((size_t)b * SEQ + row) * DMODEL + hd * DK;
        Oa[base + q31]      = f2bf(oacc0[r] / lq);
        Oa[base + 32 + q31] = f2bf(oacc1[r] / lq);
    }
}

extern "C" void kernel_launch(void* const* d_in, const int* in_sizes, int n_in,
                              void* d_out, int out_size, void* d_ws, size_t ws_size,
                              hipStream_t stream) {
    (void)in_sizes; (void)n_in; (void)out_size; (void)ws_size;
    const float* x  = (const float*)d_in[0];
    const int* mask = (const int*)d_in[1];
    const float* Wq = (const float*)d_in[2];
    const float* bq = (const float*)d_in[3];
    const float* Wk = (const float*)d_in[4];
    const float* bk = (const float*)d_in[5];
    const float* Wv = (const float*)d_in[6];
    const float* bv = (const float*)d_in[7];
    const float* Wo = (const float*)d_in[8];
    const float* bo = (const float*)d_in[9];
    float* out = (float*)d_out;

    char* ws = (char*)d_ws;
    unsigned short* xb  = (unsigned short*)(ws);                                   // 8192x1024 bf16
    unsigned short* wqb = (unsigned short*)(ws + 16777216);                        // 1024x1024 bf16
    unsigned short* wkb = (unsigned short*)(ws + 16777216 + 1 * 2097152);
    unsigned short* wvb = (unsigned short*)(ws + 16777216 + 2 * 2097152);
    unsigned short* wob = (unsigned short*)(ws + 16777216 + 3 * 2097152);
    unsigned short* qb  = (unsigned short*)(ws + 16777216 + 4 * 2097152);          // [BH,L,64]
    unsigned short* kb  = qb  + (size_t)MROWS * DMODEL;                            // [BH,L,64]
    unsigned short* vtb = kb  + (size_t)MROWS * DMODEL;                            // blocked V
    unsigned short* ab  = vtb + (size_t)MROWS * DMODEL;                            // [B,L,DMODEL]
    float*          mbf = (float*)(ab + (size_t)MROWS * DMODEL);                   // [B,L]

    // 4 launches: prep (x/W cvt + mask bias), QKV gemm, flash, O-proj gemm
    prep_kernel<<<dim3(XBLK + WBLK + MBLK), 256, 0, stream>>>(
        x, Wq, Wk, Wv, Wo, mask, xb, wqb, wkb, wvb, wob, mbf);

    gemm128<0><<<dim3(24, MROWS / 128), 256, 0, stream>>>(
        xb, wqb, wkb, wvb, bq, bk, bv, qb, kb, vtb);

    flash_attn<<<dim3(16, BATCH * NHEADS), 256, 0, stream>>>(qb, kb, vtb, mbf, ab);

    gemm128<1><<<dim3(8, MROWS / 128), 256, 0, stream>>>(
        ab, wob, nullptr, nullptr, bo, nullptr, nullptr, out, nullptr, nullptr);
}